// Round 16
// baseline (303.646 us; speedup 1.0000x reference)
//
#include <hip/hip_runtime.h>

#define T_TOK 4096
#define H_DIM 2048
#define I_DIM 1408
#define E_NUM 8
#define NPAIR 8192
#define BM 128
#define BK 64
#define NT1 32        // 2048/64
#define NT2 22        // 1408/64
#define G1_BLOCKS 1584  // 72 tiles x 22 N-blocks (N=64); 1584 = 8 XCD x 198
#define G2_BLOCKS 1152  // 72 tiles x 16 N-blocks (N=128); 1152 = 8 XCD x 144
#define PREP_BLOCKS 2737  // 688 band-transpose + 1 build + 2048 conv

typedef float f32x4 __attribute__((ext_vector_type(4)));
typedef short s16x8 __attribute__((ext_vector_type(8)));

static __device__ __forceinline__ short f2bf(float f) {
  union { float f; unsigned u; } c; c.f = f;
  unsigned r = c.u + 0x7FFFu + ((c.u >> 16) & 1u);
  return (short)(r >> 16);
}

// global -> LDS direct, 16B per lane. LDS dest = wave-uniform base + lane*16.
#define GLD16(g, l) __builtin_amdgcn_global_load_lds( \
    (const __attribute__((address_space(1))) void*)(g), \
    (__attribute__((address_space(3))) void*)(l), 16, 0, 0)

// ============ merged prepass: transposes FIRST, then build, then conv ============
// Weight layout out: [K/64][N][64] bf16. Transpose v7 (page-granule): band =
// 64 k-rows (one k-chunk), strip = 256 cols -> each staging wave-instr reads a
// FULL 1KB contiguous row segment (1 DRAM page activation per KB instead of
// per 512B). Writes: thread t emits one full 128B line, block-sequential.
__global__ __launch_bounds__(256) void moe_prep(
    const float* __restrict__ hidden, const float* __restrict__ Wg,
    const float* __restrict__ Wu, const float* __restrict__ Wd,
    const int* __restrict__ idx, const float* __restrict__ wts,
    short* __restrict__ hb, short* __restrict__ wgt,
    short* __restrict__ wut, short* __restrict__ wdt,
    int* __restrict__ tok_s, float* __restrict__ wt_s, int* __restrict__ inv,
    int* __restrict__ tile_e, int* __restrict__ tile_r0,
    int* __restrict__ tile_r1, int* __restrict__ ntiles) {
  __shared__ float tf[64 * 256];        // 64 KB strip buffer
  __shared__ int cnt[E_NUM], cur[E_NUM];
  int b = blockIdx.x, tid = threadIdx.x;

  if (b == 688) {                       // ---- build (mid-grid, tail hidden) ----
    if (tid < E_NUM) cnt[tid] = 0;
    __syncthreads();
    for (int p = tid; p < NPAIR; p += 256) atomicAdd(&cnt[idx[p] & 7], 1);
    __syncthreads();
    if (tid == 0) {
      int o = 0, nt = 0;
      for (int e = 0; e < E_NUM; e++) {
        cur[e] = o;
        int c = cnt[e];
        for (int m0 = 0; m0 < c; m0 += BM) {
          tile_e[nt] = e;
          tile_r0[nt] = o + m0;
          tile_r1[nt] = o + ((m0 + BM < c) ? (m0 + BM) : c);
          nt++;
        }
        o += c;
      }
      *ntiles = nt;
    }
    __syncthreads();
    for (int p = tid; p < NPAIR; p += 256) {
      int e = idx[p] & 7;
      int pos = atomicAdd(&cur[e], 1);
      tok_s[pos] = p >> 1;
      wt_s[pos]  = wts[p];
      inv[p]     = pos;
    }
    return;
  }
  if (b > 688) {                        // ---- conv hidden ----
    size_t i = ((size_t)(b - 689) * 256 + tid) * 16;
    const f32x4* s = (const f32x4*)(hidden + i);
    f32x4 a = s[0], bb = s[1], c = s[2], d = s[3];
    s16x8 v0, v1;
    v0[0]=f2bf(a[0]); v0[1]=f2bf(a[1]); v0[2]=f2bf(a[2]); v0[3]=f2bf(a[3]);
    v0[4]=f2bf(bb[0]); v0[5]=f2bf(bb[1]); v0[6]=f2bf(bb[2]); v0[7]=f2bf(bb[3]);
    v1[0]=f2bf(c[0]); v1[1]=f2bf(c[1]); v1[2]=f2bf(c[2]); v1[3]=f2bf(c[3]);
    v1[4]=f2bf(d[0]); v1[5]=f2bf(d[1]); v1[6]=f2bf(d[2]); v1[7]=f2bf(d[3]);
    *(s16x8*)(hb + i) = v0;
    *(s16x8*)(hb + i + 8) = v1;
    return;
  }
  // ---- page-granule transpose (blocks 0..687): 64-row band, 256-col strips ----
  int lb = b;
  const float* src; short* dst; int N, kb, nfull, tail;
  if (lb < 512) {
    src = (lb < 256) ? Wg : Wu;
    dst = (lb < 256) ? wgt : wut;
    int l = lb & 255;
    int e = l >> 5; kb = l & 31;
    N = I_DIM; nfull = 5; tail = 1;          // 5*256 + 128
    src += (size_t)e * ((size_t)H_DIM * I_DIM);
    dst += (size_t)e * ((size_t)H_DIM * I_DIM);
  } else {
    int l = lb - 512;
    int e = l / 22; kb = l % 22;
    src = Wd; dst = wdt; N = H_DIM; nfull = 8; tail = 0;   // 8*256
    src += (size_t)e * ((size_t)I_DIM * H_DIM);
    dst += (size_t)e * ((size_t)I_DIM * H_DIM);
  }
  int lane = tid & 63, wv = tid >> 6;
  const float* rowbase = src + (size_t)(kb * 64) * N;

  for (int s = 0; s < nfull; s++) {
    int s0 = s << 8;
    // stage: one wave-instr = one FULL 1KB row segment (page-granule read)
    #pragma unroll
    for (int j = 0; j < 16; j++) {
      int r = wv * 16 + j;
      GLD16(rowbase + (size_t)r * N + s0 + lane * 4, tf + r * 256);
    }
    __syncthreads();
    // process: thread t = col; reads contiguous-per-wave (conflict-free),
    // writes one full 128B line, block-sequential across t.
    short* op = dst + ((size_t)kb * N + s0 + tid) * 64;
    #pragma unroll
    for (int q = 0; q < 8; q++) {
      s16x8 o;
      #pragma unroll
      for (int j2 = 0; j2 < 8; j2++) o[j2] = f2bf(tf[(q * 8 + j2) * 256 + tid]);
      *(s16x8*)(op + q * 8) = o;
    }
    __syncthreads();
  }
  if (tail) {                            // last 128 cols (N=1408)
    int s0 = nfull << 8;                 // 1280
    #pragma unroll
    for (int j = 0; j < 8; j++) {
      int pr = wv * 8 + j;               // row pair: rows 2pr, 2pr+1
      int r = 2 * pr + (lane >> 5);
      GLD16(rowbase + (size_t)r * N + s0 + (lane & 31) * 4, tf + pr * 256);
    }
    __syncthreads();
    int col = tid & 127, kh = tid >> 7;
    short* op = dst + ((size_t)kb * N + s0 + col) * 64 + kh * 32;
    #pragma unroll
    for (int q = 0; q < 4; q++) {
      s16x8 o;
      #pragma unroll
      for (int j2 = 0; j2 < 8; j2++) {
        int r = kh * 32 + q * 8 + j2;
        o[j2] = f2bf(tf[(r >> 1) * 256 + (r & 1) * 128 + col]);
      }
      *(s16x8*)(op + q * 8) = o;
    }
  }
}

// ---------------- GEMM1: act = silu(X@Wg) * (X@Wu), all bf16 ----------------
// Tile 128(M) x 64(N) x 64(K); B in blocked [K/64][I][64] layout.
__global__ __launch_bounds__(256, 2) void moe_gemm1(
    const short* __restrict__ hb, const short* __restrict__ Wgt,
    const short* __restrict__ Wut, const int* __restrict__ tok_s,
    const int* __restrict__ tile_e, const int* __restrict__ tile_r0,
    const int* __restrict__ tile_r1, const int* __restrict__ ntiles,
    short* __restrict__ act) {
  __shared__ short As[BM * BK];
  __shared__ short Bg[64 * BK];
  __shared__ short Bu[64 * BK];
  // bijective XCD-chunk swizzle: 1584 = 8 * 198; N (22) fastest within chunk
  int L = (blockIdx.x & 7) * (G1_BLOCKS / 8) + (blockIdx.x >> 3);
  int bt = L / 22;
  if (bt >= *ntiles) return;
  int e = tile_e[bt], r0 = tile_r0[bt], r1 = tile_r1[bt];
  int n0 = (L % 22) * 64;
  const short* wg = Wgt + (size_t)e * ((size_t)H_DIM * I_DIM);
  const short* wu = Wut + (size_t)e * ((size_t)H_DIM * I_DIM);

  int tid = threadIdx.x, lane = tid & 63, wv = tid >> 6;
  int l3 = lane >> 3;
  int k8 = (((lane & 7) ^ l3) << 3);   // inverse-swizzled source k-chunk

  const short *a_src[4], *g_src[2], *u_src[2];
  short *a_dst[4], *g_dst[2], *u_dst[2];
  #pragma unroll
  for (int s = 0; s < 4; s++) {
    int row = wv * 32 + s * 8 + l3;
    int p = r0 + row; if (p > NPAIR - 1) p = NPAIR - 1;
    a_src[s] = hb + (size_t)tok_s[p] * H_DIM + k8;
    a_dst[s] = As + (wv * 32 + s * 8) * BK;
  }
  #pragma unroll
  for (int s = 0; s < 2; s++) {
    int row = wv * 16 + s * 8 + l3;
    g_src[s] = wg + (size_t)(n0 + row) * 64 + k8;   // blocked layout
    u_src[s] = wu + (size_t)(n0 + row) * 64 + k8;
    g_dst[s] = Bg + (wv * 16 + s * 8) * BK;
    u_dst[s] = Bu + (wv * 16 + s * 8) * BK;
  }

  int wm = wv >> 1, wn = wv & 1;
  int lrow = lane & 15, lk = lane >> 4;
  int ch0 = ((lk ^ (lrow & 7)) << 3);
  int ch1 = (((4 + lk) ^ (lrow & 7)) << 3);

  f32x4 accg[4][2], accu[4][2];
  #pragma unroll
  for (int i = 0; i < 4; i++)
    #pragma unroll
    for (int j = 0; j < 2; j++) { accg[i][j] = 0; accu[i][j] = 0; }

  #define G1_STAGE(t) do { int ka = (t) << 6; int kbb = (t) * (I_DIM << 6); \
    GLD16(a_src[0]+ka, a_dst[0]); GLD16(a_src[1]+ka, a_dst[1]); \
    GLD16(a_src[2]+ka, a_dst[2]); GLD16(a_src[3]+ka, a_dst[3]); \
    GLD16(g_src[0]+kbb, g_dst[0]); GLD16(g_src[1]+kbb, g_dst[1]); \
    GLD16(u_src[0]+kbb, u_dst[0]); GLD16(u_src[1]+kbb, u_dst[1]); } while (0)

  #define G1_RD(ch, af, bgf, buf_) do { \
    _Pragma("unroll") \
    for (int mf = 0; mf < 4; mf++) \
      af[mf] = *(const s16x8*)&As[(wm * 64 + mf * 16 + lrow) * BK + (ch)]; \
    _Pragma("unroll") \
    for (int nf = 0; nf < 2; nf++) { \
      int oo = (wn * 32 + nf * 16 + lrow) * BK + (ch); \
      bgf[nf] = *(const s16x8*)&Bg[oo]; \
      buf_[nf] = *(const s16x8*)&Bu[oo]; } } while (0)

  #define G1_MFMA(af, bgf, buf_) do { \
    _Pragma("unroll") \
    for (int mf = 0; mf < 4; mf++) \
      _Pragma("unroll") \
      for (int nf = 0; nf < 2; nf++) { \
        accg[mf][nf] = __builtin_amdgcn_mfma_f32_16x16x32_bf16(af[mf], bgf[nf], accg[mf][nf], 0, 0, 0); \
        accu[mf][nf] = __builtin_amdgcn_mfma_f32_16x16x32_bf16(af[mf], buf_[nf], accu[mf][nf], 0, 0, 0); } } while (0)

  G1_STAGE(0);
  __syncthreads();
  for (int t = 0; t < NT1 - 1; ++t) {
    s16x8 a0[4], bg0[2], bu0[2];
    G1_RD(ch0, a0, bg0, bu0);
    G1_MFMA(a0, bg0, bu0);
    s16x8 a1[4], bg1[2], bu1[2];
    G1_RD(ch1, a1, bg1, bu1);
    __syncthreads();                       // all reads of tile t retired
    G1_STAGE(t + 1);                       // overwrite buffer; loads in flight
    __builtin_amdgcn_sched_barrier(0);     // keep load issue above the MFMAs
    G1_MFMA(a1, bg1, bu1);                 // overlaps global->LDS latency
    __syncthreads();                       // drains vmcnt(0): tile t+1 ready
  }
  {
    s16x8 a0[4], bg0[2], bu0[2];
    G1_RD(ch0, a0, bg0, bu0);
    G1_MFMA(a0, bg0, bu0);
    s16x8 a1[4], bg1[2], bu1[2];
    G1_RD(ch1, a1, bg1, bu1);
    G1_MFMA(a1, bg1, bu1);
  }

  #pragma unroll
  for (int mf = 0; mf < 4; mf++) {
    int rb = r0 + wm * 64 + mf * 16 + (lk << 2);
    #pragma unroll
    for (int nf = 0; nf < 2; nf++) {
      int col = n0 + wn * 32 + nf * 16 + lrow;
      #pragma unroll
      for (int j = 0; j < 4; j++) {
        int p = rb + j;
        if (p < r1) {
          float g = accg[mf][nf][j], u = accu[mf][nf][j];
          float s = g / (1.f + __expf(-g)) * u;
          act[p * I_DIM + col] = f2bf(s);
        }
      }
    }
  }
}

// ---------------- GEMM2: y[pos] = act[pos] @ Wd, plain fp32 stores ----------------
__global__ __launch_bounds__(256, 2) void moe_gemm2(
    const short* __restrict__ act, const short* __restrict__ Wdt,
    const int* __restrict__ tile_e, const int* __restrict__ tile_r0,
    const int* __restrict__ tile_r1, const int* __restrict__ ntiles,
    float* __restrict__ y) {
  __shared__ short As[BM * BK];
  __shared__ short Bd[BM * BK];
  // bijective XCD-chunk swizzle: 1152 = 8 * 144; N (16) fastest within chunk
  int L = (blockIdx.x & 7) * (G2_BLOCKS / 8) + (blockIdx.x >> 3);
  int bt = L >> 4;
  if (bt >= *ntiles) return;
  int e = tile_e[bt], r0 = tile_r0[bt], r1 = tile_r1[bt];
  int n0 = (L & 15) * 128;
  const short* wd = Wdt + (size_t)e * ((size_t)H_DIM * I_DIM);

  int tid = threadIdx.x, lane = tid & 63, wv = tid >> 6;
  int l3 = lane >> 3;
  int k8 = (((lane & 7) ^ l3) << 3);

  const short *a_src[4], *b_src[4];
  short *a_dst[4], *b_dst[4];
  #pragma unroll
  for (int s = 0; s < 4; s++) {
    int row = wv * 32 + s * 8 + l3;
    int p = r0 + row; if (p > NPAIR - 1) p = NPAIR - 1;
    a_src[s] = act + (size_t)p * I_DIM + k8;
    b_src[s] = wd + (size_t)(n0 + row) * 64 + k8;   // blocked layout
    a_dst[s] = As + (wv * 32 + s * 8) * BK;
    b_dst[s] = Bd + (wv * 32 + s * 8) * BK;
  }

  int wm = wv >> 1, wn = wv & 1;
  int lrow = lane & 15, lk = lane >> 4;
  int ch0 = ((lk ^ (lrow & 7)) << 3);
  int ch1 = (((4 + lk) ^ (lrow & 7)) << 3);

  f32x4 acc[4][4];
  #pragma unroll
  for (int i = 0; i < 4; i++)
    #pragma unroll
    for (int j = 0; j < 4; j++) acc[i][j] = 0;

  #define G2_STAGE(t) do { int ka = (t) << 6; int kbb = (t) * (H_DIM << 6); \
    GLD16(a_src[0]+ka, a_dst[0]); GLD16(a_src[1]+ka, a_dst[1]); \
    GLD16(a_src[2]+ka, a_dst[2]); GLD16(a_src[3]+ka, a_dst[3]); \
    GLD16(b_src[0]+kbb, b_dst[0]); GLD16(b_src[1]+kbb, b_dst[1]); \
    GLD16(b_src[2]+kbb, b_dst[2]); GLD16(b_src[3]+kbb, b_dst[3]); } while (0)

  #define G2_RD(ch, af, bf) do { \
    _Pragma("unroll") \
    for (int mf = 0; mf < 4; mf++) \
      af[mf] = *(const s16x8*)&As[(wm * 64 + mf * 16 + lrow) * BK + (ch)]; \
    _Pragma("unroll") \
    for (int nf = 0; nf < 4; nf++) \
      bf[nf] = *(const s16x8*)&Bd[(wn * 64 + nf * 16 + lrow) * BK + (ch)]; } while (0)

  #define G2_MFMA(af, bf) do { \
    _Pragma("unroll") \
    for (int mf = 0; mf < 4; mf++) \
      _Pragma("unroll") \
      for (int nf = 0; nf < 4; nf++) \
        acc[mf][nf] = __builtin_amdgcn_mfma_f32_16x16x32_bf16(af[mf], bf[nf], acc[mf][nf], 0, 0, 0); } while (0)

  G2_STAGE(0);
  __syncthreads();
  for (int t = 0; t < NT2 - 1; ++t) {
    s16x8 a0[4], b0[4];
    G2_RD(ch0, a0, b0);
    G2_MFMA(a0, b0);
    s16x8 a1[4], b1[4];
    G2_RD(ch1, a1, b1);
    __syncthreads();
    G2_STAGE(t + 1);
    __builtin_amdgcn_sched_barrier(0);
    G2_MFMA(a1, b1);
    __syncthreads();
  }
  {
    s16x8 a0[4], b0[4];
    G2_RD(ch0, a0, b0);
    G2_MFMA(a0, b0);
    s16x8 a1[4], b1[4];
    G2_RD(ch1, a1, b1);
    G2_MFMA(a1, b1);
  }

  #pragma unroll
  for (int mf = 0; mf < 4; mf++) {
    int rb = r0 + wm * 64 + mf * 16 + (lk << 2);
    #pragma unroll
    for (int nf = 0; nf < 4; nf++) {
      int col = n0 + wn * 64 + nf * 16 + lrow;
      #pragma unroll
      for (int j = 0; j < 4; j++) {
        int p = rb + j;
        if (p < r1) {
          y[(size_t)p * H_DIM + col] = acc[mf][nf][j];
        }
      }
    }
  }
}

// ---------------- combine: out[t] = w0*y[inv[2t]] + w1*y[inv[2t+1]] ----------------
__global__ __launch_bounds__(256) void moe_combine(
    const float* __restrict__ y, const int* __restrict__ inv,
    const float* __restrict__ wt_s, float* __restrict__ out) {
  int t = blockIdx.x;
  int p0 = inv[2 * t], p1 = inv[2 * t + 1];
  float w0 = wt_s[p0], w1 = wt_s[p1];
  const f32x4* y0 = (const f32x4*)(y + (size_t)p0 * H_DIM);
  const f32x4* y1 = (const f32x4*)(y + (size_t)p1 * H_DIM);
  f32x4* o = (f32x4*)(out + (size_t)t * H_DIM);
  int i = threadIdx.x;
  f32x4 a0 = y0[i], b0 = y1[i];
  f32x4 a1 = y0[i + 256], b1 = y1[i + 256];
  o[i] = w0 * a0 + w1 * b0;
  o[i + 256] = w0 * a1 + w1 * b1;
}

extern "C" void kernel_launch(void* const* d_in, const int* in_sizes, int n_in,
                              void* d_out, int out_size, void* d_ws, size_t ws_size,
                              hipStream_t stream) {
  const float* hidden = (const float*)d_in[0];
  const int*   idx    = (const int*)d_in[1];
  const float* wts    = (const float*)d_in[2];
  const float* Wg     = (const float*)d_in[3];
  const float* Wu     = (const float*)d_in[4];
  const float* Wd     = (const float*)d_in[5];
  float* out = (float*)d_out;

  char* ws = (char*)d_ws;
  int*   tok_s   = (int*)(ws);
  float* wt_s    = (float*)(ws + 32768);
  int*   tile_e  = (int*)(ws + 65536);
  int*   tile_r0 = (int*)(ws + 66048);
  int*   tile_r1 = (int*)(ws + 66560);
  int*   ntiles  = (int*)(ws + 67072);
  int*   inv     = (int*)(ws + 131072);

  const size_t OFF_HB  = 1ull << 20;
  const size_t OFF_WGT = OFF_HB  + 16777216ull;
  const size_t OFF_WUT = OFF_WGT + 46137344ull;
  const size_t OFF_WDT = OFF_WUT + 46137344ull;
  const size_t OFF_ACT = OFF_WDT + 46137344ull;

  short* hb  = (short*)(ws + OFF_HB);
  short* wgt = (short*)(ws + OFF_WGT);
  short* wut = (short*)(ws + OFF_WUT);
  short* wdt = (short*)(ws + OFF_WDT);
  short* act = (short*)(ws + OFF_ACT);
  // y aliases wgt+wut (dead after moe_gemm1; same-stream ordering).
  float* y   = (float*)(ws + OFF_WGT);

  moe_prep<<<PREP_BLOCKS, 256, 0, stream>>>(hidden, Wg, Wu, Wd, idx, wts,
      hb, wgt, wut, wdt, tok_s, wt_s, inv, tile_e, tile_r0, tile_r1, ntiles);
  moe_gemm1<<<G1_BLOCKS, 256, 0, stream>>>(hb, wgt, wut, tok_s,
      tile_e, tile_r0, tile_r1, ntiles, act);
  moe_gemm2<<<G2_BLOCKS, 256, 0, stream>>>(act, wdt,
      tile_e, tile_r0, tile_r1, ntiles, y);
  moe_combine<<<T_TOK, 256, 0, stream>>>(y, inv, wt_s, out);
}

// Round 17
// 289.271 us; speedup vs baseline: 1.0497x; 1.0497x over previous
//
#include <hip/hip_runtime.h>

#define T_TOK 4096
#define H_DIM 2048
#define I_DIM 1408
#define E_NUM 8
#define NPAIR 8192
#define BM 128
#define BK 64
#define NT1 32        // 2048/64
#define NT2 22        // 1408/64
#define G1_BLOCKS 1584  // 72 tiles x 22 N-blocks (N=64); 1584 = 8 XCD x 198
#define G2_BLOCKS 1152  // 72 tiles x 16 N-blocks (N=128); 1152 = 8 XCD x 144
#define PREP_BLOCKS 2737  // 688 band-transpose + 1 build + 2048 conv

typedef float f32x4 __attribute__((ext_vector_type(4)));
typedef short s16x8 __attribute__((ext_vector_type(8)));

static __device__ __forceinline__ short f2bf(float f) {
  union { float f; unsigned u; } c; c.f = f;
  unsigned r = c.u + 0x7FFFu + ((c.u >> 16) & 1u);
  return (short)(r >> 16);
}
static __device__ __forceinline__ float bf2f(short s) {
  union { unsigned u; float f; } c;
  c.u = ((unsigned)(unsigned short)s) << 16;
  return c.f;
}

// global -> LDS direct, 16B per lane. LDS dest = wave-uniform base + lane*16.
#define GLD16(g, l) __builtin_amdgcn_global_load_lds( \
    (const __attribute__((address_space(1))) void*)(g), \
    (__attribute__((address_space(3))) void*)(l), 16, 0, 0)

// ============ merged prepass: transposes FIRST, then build, then conv ============
// Weight layout out: [K/64][N][64] bf16. Transpose = r15's double-buffered
// 128-col-strip variant (best measured config; the ~135us is the structural
// cost of the strided side of the reshape -- 7 variants agree).
__global__ __launch_bounds__(256) void moe_prep(
    const float* __restrict__ hidden, const float* __restrict__ Wg,
    const float* __restrict__ Wu, const float* __restrict__ Wd,
    const int* __restrict__ idx, const float* __restrict__ wts,
    short* __restrict__ hb, short* __restrict__ wgt,
    short* __restrict__ wut, short* __restrict__ wdt,
    int* __restrict__ tok_s, float* __restrict__ wt_s, int* __restrict__ inv,
    int* __restrict__ tile_e, int* __restrict__ tile_r0,
    int* __restrict__ tile_r1, int* __restrict__ ntiles) {
  __shared__ float tf[2][8192];         // 2 x 32 KB strip buffers
  __shared__ int cnt[E_NUM], cur[E_NUM];
  int b = blockIdx.x, tid = threadIdx.x;

  if (b == 688) {                       // ---- build (mid-grid, tail hidden) ----
    if (tid < E_NUM) cnt[tid] = 0;
    __syncthreads();
    for (int p = tid; p < NPAIR; p += 256) atomicAdd(&cnt[idx[p] & 7], 1);
    __syncthreads();
    if (tid == 0) {
      int o = 0, nt = 0;
      for (int e = 0; e < E_NUM; e++) {
        cur[e] = o;
        int c = cnt[e];
        for (int m0 = 0; m0 < c; m0 += BM) {
          tile_e[nt] = e;
          tile_r0[nt] = o + m0;
          tile_r1[nt] = o + ((m0 + BM < c) ? (m0 + BM) : c);
          nt++;
        }
        o += c;
      }
      *ntiles = nt;
    }
    __syncthreads();
    for (int p = tid; p < NPAIR; p += 256) {
      int e = idx[p] & 7;
      int pos = atomicAdd(&cur[e], 1);
      tok_s[pos] = p >> 1;
      wt_s[pos]  = wts[p];
      inv[p]     = pos;
    }
    return;
  }
  if (b > 688) {                        // ---- conv hidden ----
    size_t i = ((size_t)(b - 689) * 256 + tid) * 16;
    const f32x4* s = (const f32x4*)(hidden + i);
    f32x4 a = s[0], bb = s[1], c = s[2], d = s[3];
    s16x8 v0, v1;
    v0[0]=f2bf(a[0]); v0[1]=f2bf(a[1]); v0[2]=f2bf(a[2]); v0[3]=f2bf(a[3]);
    v0[4]=f2bf(bb[0]); v0[5]=f2bf(bb[1]); v0[6]=f2bf(bb[2]); v0[7]=f2bf(bb[3]);
    v1[0]=f2bf(c[0]); v1[1]=f2bf(c[1]); v1[2]=f2bf(c[2]); v1[3]=f2bf(c[3]);
    v1[4]=f2bf(d[0]); v1[5]=f2bf(d[1]); v1[6]=f2bf(d[2]); v1[7]=f2bf(d[3]);
    *(s16x8*)(hb + i) = v0;
    *(s16x8*)(hb + i + 8) = v1;
    return;
  }
  // ---- looping transpose (blocks 0..687): one 64-row band, 128-col strips ----
  int lb = b;
  const float* src; short* dst; int N, kb, nstrips;
  if (lb < 512) {
    src = (lb < 256) ? Wg : Wu;
    dst = (lb < 256) ? wgt : wut;
    int l = lb & 255;
    int e = l >> 5; kb = l & 31;
    N = I_DIM; nstrips = 11;
    src += (size_t)e * ((size_t)H_DIM * I_DIM);
    dst += (size_t)e * ((size_t)H_DIM * I_DIM);
  } else {
    int l = lb - 512;
    int e = l / 22; kb = l % 22;
    src = Wd; dst = wdt; N = H_DIM; nstrips = 16;
    src += (size_t)e * ((size_t)I_DIM * H_DIM);
    dst += (size_t)e * ((size_t)I_DIM * H_DIM);
  }
  int lane = tid & 63, wv = tid >> 6;
  int srow = wv * 16 + (lane >> 5);
  const float* g0 = src + (size_t)(kb * 64 + srow) * N + (lane & 31) * 4;

  #define TSTAGE(buf, strip) do { \
    const float* gs = g0 + (strip) * 128; \
    float* ld = (buf) + (wv * 8) * 256; \
    _Pragma("unroll") \
    for (int j = 0; j < 8; j++) \
      GLD16(gs + (size_t)(2 * j) * N, ld + j * 256); } while (0)

  int n = tid >> 1, h = tid & 1;
  TSTAGE(tf[0], 0);
  __syncthreads();                       // strip 0 staged
  for (int sj = 0; sj < nstrips; sj++) {
    if (sj + 1 < nstrips) TSTAGE(tf[(sj + 1) & 1], sj + 1);
    const float* tb = tf[sj & 1];
    float v[32];
    #pragma unroll
    for (int i = 0; i < 32; i++) v[i] = tb[(h * 32 + i) * 128 + n];
    s16x8 o0, o1, o2, o3;
    #pragma unroll
    for (int j = 0; j < 8; j++) {
      o0[j] = f2bf(v[j]);      o1[j] = f2bf(v[8 + j]);
      o2[j] = f2bf(v[16 + j]); o3[j] = f2bf(v[24 + j]);
    }
    short* op = dst + ((size_t)kb * N + sj * 128) * 64 + tid * 32;
    *(s16x8*)(op)      = o0;
    *(s16x8*)(op + 8)  = o1;
    *(s16x8*)(op + 16) = o2;
    *(s16x8*)(op + 24) = o3;
    __syncthreads();                     // reads done + next strip staged
  }
  #undef TSTAGE
}

// ---------------- GEMM1: act = silu(X@Wg) * (X@Wu), all bf16 ----------------
// Tile 128(M) x 64(N) x 64(K); B in blocked [K/64][I][64] layout.
__global__ __launch_bounds__(256, 2) void moe_gemm1(
    const short* __restrict__ hb, const short* __restrict__ Wgt,
    const short* __restrict__ Wut, const int* __restrict__ tok_s,
    const int* __restrict__ tile_e, const int* __restrict__ tile_r0,
    const int* __restrict__ tile_r1, const int* __restrict__ ntiles,
    short* __restrict__ act) {
  __shared__ short As[BM * BK];
  __shared__ short Bg[64 * BK];
  __shared__ short Bu[64 * BK];
  // bijective XCD-chunk swizzle: 1584 = 8 * 198; N (22) fastest within chunk
  int L = (blockIdx.x & 7) * (G1_BLOCKS / 8) + (blockIdx.x >> 3);
  int bt = L / 22;
  if (bt >= *ntiles) return;
  int e = tile_e[bt], r0 = tile_r0[bt], r1 = tile_r1[bt];
  int n0 = (L % 22) * 64;
  const short* wg = Wgt + (size_t)e * ((size_t)H_DIM * I_DIM);
  const short* wu = Wut + (size_t)e * ((size_t)H_DIM * I_DIM);

  int tid = threadIdx.x, lane = tid & 63, wv = tid >> 6;
  int l3 = lane >> 3;
  int k8 = (((lane & 7) ^ l3) << 3);   // inverse-swizzled source k-chunk

  const short *a_src[4], *g_src[2], *u_src[2];
  short *a_dst[4], *g_dst[2], *u_dst[2];
  #pragma unroll
  for (int s = 0; s < 4; s++) {
    int row = wv * 32 + s * 8 + l3;
    int p = r0 + row; if (p > NPAIR - 1) p = NPAIR - 1;
    a_src[s] = hb + (size_t)tok_s[p] * H_DIM + k8;
    a_dst[s] = As + (wv * 32 + s * 8) * BK;
  }
  #pragma unroll
  for (int s = 0; s < 2; s++) {
    int row = wv * 16 + s * 8 + l3;
    g_src[s] = wg + (size_t)(n0 + row) * 64 + k8;   // blocked layout
    u_src[s] = wu + (size_t)(n0 + row) * 64 + k8;
    g_dst[s] = Bg + (wv * 16 + s * 8) * BK;
    u_dst[s] = Bu + (wv * 16 + s * 8) * BK;
  }

  int wm = wv >> 1, wn = wv & 1;
  int lrow = lane & 15, lk = lane >> 4;
  int ch0 = ((lk ^ (lrow & 7)) << 3);
  int ch1 = (((4 + lk) ^ (lrow & 7)) << 3);

  f32x4 accg[4][2], accu[4][2];
  #pragma unroll
  for (int i = 0; i < 4; i++)
    #pragma unroll
    for (int j = 0; j < 2; j++) { accg[i][j] = 0; accu[i][j] = 0; }

  #define G1_STAGE(t) do { int ka = (t) << 6; int kbb = (t) * (I_DIM << 6); \
    GLD16(a_src[0]+ka, a_dst[0]); GLD16(a_src[1]+ka, a_dst[1]); \
    GLD16(a_src[2]+ka, a_dst[2]); GLD16(a_src[3]+ka, a_dst[3]); \
    GLD16(g_src[0]+kbb, g_dst[0]); GLD16(g_src[1]+kbb, g_dst[1]); \
    GLD16(u_src[0]+kbb, u_dst[0]); GLD16(u_src[1]+kbb, u_dst[1]); } while (0)

  #define G1_RD(ch, af, bgf, buf_) do { \
    _Pragma("unroll") \
    for (int mf = 0; mf < 4; mf++) \
      af[mf] = *(const s16x8*)&As[(wm * 64 + mf * 16 + lrow) * BK + (ch)]; \
    _Pragma("unroll") \
    for (int nf = 0; nf < 2; nf++) { \
      int oo = (wn * 32 + nf * 16 + lrow) * BK + (ch); \
      bgf[nf] = *(const s16x8*)&Bg[oo]; \
      buf_[nf] = *(const s16x8*)&Bu[oo]; } } while (0)

  #define G1_MFMA(af, bgf, buf_) do { \
    _Pragma("unroll") \
    for (int mf = 0; mf < 4; mf++) \
      _Pragma("unroll") \
      for (int nf = 0; nf < 2; nf++) { \
        accg[mf][nf] = __builtin_amdgcn_mfma_f32_16x16x32_bf16(af[mf], bgf[nf], accg[mf][nf], 0, 0, 0); \
        accu[mf][nf] = __builtin_amdgcn_mfma_f32_16x16x32_bf16(af[mf], buf_[nf], accu[mf][nf], 0, 0, 0); } } while (0)

  G1_STAGE(0);
  __syncthreads();
  for (int t = 0; t < NT1 - 1; ++t) {
    s16x8 a0[4], bg0[2], bu0[2];
    G1_RD(ch0, a0, bg0, bu0);
    G1_MFMA(a0, bg0, bu0);
    s16x8 a1[4], bg1[2], bu1[2];
    G1_RD(ch1, a1, bg1, bu1);
    __syncthreads();                       // all reads of tile t retired
    G1_STAGE(t + 1);                       // overwrite buffer; loads in flight
    __builtin_amdgcn_sched_barrier(0);     // keep load issue above the MFMAs
    G1_MFMA(a1, bg1, bu1);                 // overlaps global->LDS latency
    __syncthreads();                       // drains vmcnt(0): tile t+1 ready
  }
  {
    s16x8 a0[4], bg0[2], bu0[2];
    G1_RD(ch0, a0, bg0, bu0);
    G1_MFMA(a0, bg0, bu0);
    s16x8 a1[4], bg1[2], bu1[2];
    G1_RD(ch1, a1, bg1, bu1);
    G1_MFMA(a1, bg1, bu1);
  }

  #pragma unroll
  for (int mf = 0; mf < 4; mf++) {
    int rb = r0 + wm * 64 + mf * 16 + (lk << 2);
    #pragma unroll
    for (int nf = 0; nf < 2; nf++) {
      int col = n0 + wn * 32 + nf * 16 + lrow;
      #pragma unroll
      for (int j = 0; j < 4; j++) {
        int p = rb + j;
        if (p < r1) {
          float g = accg[mf][nf][j], u = accu[mf][nf][j];
          float s = g / (1.f + __expf(-g)) * u;
          act[p * I_DIM + col] = f2bf(s);
        }
      }
    }
  }
}

// ---------------- GEMM2: y[pos] = act[pos] @ Wd, bf16 stores ----------------
__global__ __launch_bounds__(256, 2) void moe_gemm2(
    const short* __restrict__ act, const short* __restrict__ Wdt,
    const int* __restrict__ tile_e, const int* __restrict__ tile_r0,
    const int* __restrict__ tile_r1, const int* __restrict__ ntiles,
    short* __restrict__ y) {
  __shared__ short As[BM * BK];
  __shared__ short Bd[BM * BK];
  // bijective XCD-chunk swizzle: 1152 = 8 * 144; N (16) fastest within chunk
  int L = (blockIdx.x & 7) * (G2_BLOCKS / 8) + (blockIdx.x >> 3);
  int bt = L >> 4;
  if (bt >= *ntiles) return;
  int e = tile_e[bt], r0 = tile_r0[bt], r1 = tile_r1[bt];
  int n0 = (L & 15) * 128;
  const short* wd = Wdt + (size_t)e * ((size_t)H_DIM * I_DIM);

  int tid = threadIdx.x, lane = tid & 63, wv = tid >> 6;
  int l3 = lane >> 3;
  int k8 = (((lane & 7) ^ l3) << 3);

  const short *a_src[4], *b_src[4];
  short *a_dst[4], *b_dst[4];
  #pragma unroll
  for (int s = 0; s < 4; s++) {
    int row = wv * 32 + s * 8 + l3;
    int p = r0 + row; if (p > NPAIR - 1) p = NPAIR - 1;
    a_src[s] = act + (size_t)p * I_DIM + k8;
    b_src[s] = wd + (size_t)(n0 + row) * 64 + k8;   // blocked layout
    a_dst[s] = As + (wv * 32 + s * 8) * BK;
    b_dst[s] = Bd + (wv * 32 + s * 8) * BK;
  }

  int wm = wv >> 1, wn = wv & 1;
  int lrow = lane & 15, lk = lane >> 4;
  int ch0 = ((lk ^ (lrow & 7)) << 3);
  int ch1 = (((4 + lk) ^ (lrow & 7)) << 3);

  f32x4 acc[4][4];
  #pragma unroll
  for (int i = 0; i < 4; i++)
    #pragma unroll
    for (int j = 0; j < 4; j++) acc[i][j] = 0;

  #define G2_STAGE(t) do { int ka = (t) << 6; int kbb = (t) * (H_DIM << 6); \
    GLD16(a_src[0]+ka, a_dst[0]); GLD16(a_src[1]+ka, a_dst[1]); \
    GLD16(a_src[2]+ka, a_dst[2]); GLD16(a_src[3]+ka, a_dst[3]); \
    GLD16(b_src[0]+kbb, b_dst[0]); GLD16(b_src[1]+kbb, b_dst[1]); \
    GLD16(b_src[2]+kbb, b_dst[2]); GLD16(b_src[3]+kbb, b_dst[3]); } while (0)

  #define G2_RD(ch, af, bf) do { \
    _Pragma("unroll") \
    for (int mf = 0; mf < 4; mf++) \
      af[mf] = *(const s16x8*)&As[(wm * 64 + mf * 16 + lrow) * BK + (ch)]; \
    _Pragma("unroll") \
    for (int nf = 0; nf < 4; nf++) \
      bf[nf] = *(const s16x8*)&Bd[(wn * 64 + nf * 16 + lrow) * BK + (ch)]; } while (0)

  #define G2_MFMA(af, bf) do { \
    _Pragma("unroll") \
    for (int mf = 0; mf < 4; mf++) \
      _Pragma("unroll") \
      for (int nf = 0; nf < 4; nf++) \
        acc[mf][nf] = __builtin_amdgcn_mfma_f32_16x16x32_bf16(af[mf], bf[nf], acc[mf][nf], 0, 0, 0); } while (0)

  G2_STAGE(0);
  __syncthreads();
  for (int t = 0; t < NT2 - 1; ++t) {
    s16x8 a0[4], b0[4];
    G2_RD(ch0, a0, b0);
    G2_MFMA(a0, b0);
    s16x8 a1[4], b1[4];
    G2_RD(ch1, a1, b1);
    __syncthreads();
    G2_STAGE(t + 1);
    __builtin_amdgcn_sched_barrier(0);
    G2_MFMA(a1, b1);
    __syncthreads();
  }
  {
    s16x8 a0[4], b0[4];
    G2_RD(ch0, a0, b0);
    G2_MFMA(a0, b0);
    s16x8 a1[4], b1[4];
    G2_RD(ch1, a1, b1);
    G2_MFMA(a1, b1);
  }

  #pragma unroll
  for (int mf = 0; mf < 4; mf++) {
    int rb = r0 + wm * 64 + mf * 16 + (lk << 2);
    #pragma unroll
    for (int nf = 0; nf < 4; nf++) {
      int col = n0 + wn * 64 + nf * 16 + lrow;
      #pragma unroll
      for (int j = 0; j < 4; j++) {
        int p = rb + j;
        if (p < r1) {
          y[(size_t)p * H_DIM + col] = f2bf(acc[mf][nf][j]);
        }
      }
    }
  }
}

// ---------------- combine: out[t] = w0*y[inv[2t]] + w1*y[inv[2t+1]] ----------------
__global__ __launch_bounds__(256) void moe_combine(
    const short* __restrict__ y, const int* __restrict__ inv,
    const float* __restrict__ wt_s, float* __restrict__ out) {
  int t = blockIdx.x;
  int p0 = inv[2 * t], p1 = inv[2 * t + 1];
  float w0 = wt_s[p0], w1 = wt_s[p1];
  int i = threadIdx.x;
  s16x8 a = *(const s16x8*)(y + (size_t)p0 * H_DIM + i * 8);
  s16x8 b = *(const s16x8*)(y + (size_t)p1 * H_DIM + i * 8);
  f32x4 r0, r1;
  #pragma unroll
  for (int j = 0; j < 4; j++) {
    r0[j] = w0 * bf2f(a[j])     + w1 * bf2f(b[j]);
    r1[j] = w0 * bf2f(a[4 + j]) + w1 * bf2f(b[4 + j]);
  }
  f32x4* o = (f32x4*)(out + (size_t)t * H_DIM + i * 8);
  o[0] = r0;
  o[1] = r1;
}

extern "C" void kernel_launch(void* const* d_in, const int* in_sizes, int n_in,
                              void* d_out, int out_size, void* d_ws, size_t ws_size,
                              hipStream_t stream) {
  const float* hidden = (const float*)d_in[0];
  const int*   idx    = (const int*)d_in[1];
  const float* wts    = (const float*)d_in[2];
  const float* Wg     = (const float*)d_in[3];
  const float* Wu     = (const float*)d_in[4];
  const float* Wd     = (const float*)d_in[5];
  float* out = (float*)d_out;

  char* ws = (char*)d_ws;
  int*   tok_s   = (int*)(ws);
  float* wt_s    = (float*)(ws + 32768);
  int*   tile_e  = (int*)(ws + 65536);
  int*   tile_r0 = (int*)(ws + 66048);
  int*   tile_r1 = (int*)(ws + 66560);
  int*   ntiles  = (int*)(ws + 67072);
  int*   inv     = (int*)(ws + 131072);

  const size_t OFF_HB  = 1ull << 20;
  const size_t OFF_WGT = OFF_HB  + 16777216ull;
  const size_t OFF_WUT = OFF_WGT + 46137344ull;
  const size_t OFF_WDT = OFF_WUT + 46137344ull;
  const size_t OFF_ACT = OFF_WDT + 46137344ull;

  short* hb  = (short*)(ws + OFF_HB);
  short* wgt = (short*)(ws + OFF_WGT);
  short* wut = (short*)(ws + OFF_WUT);
  short* wdt = (short*)(ws + OFF_WDT);
  short* act = (short*)(ws + OFF_ACT);
  // y (bf16, 33.5 MB) aliases wgt (dead after moe_gemm1; same-stream ordering).
  short* y   = (short*)(ws + OFF_WGT);

  moe_prep<<<PREP_BLOCKS, 256, 0, stream>>>(hidden, Wg, Wu, Wd, idx, wts,
      hb, wgt, wut, wdt, tok_s, wt_s, inv, tile_e, tile_r0, tile_r1, ntiles);
  moe_gemm1<<<G1_BLOCKS, 256, 0, stream>>>(hb, wgt, wut, tok_s,
      tile_e, tile_r0, tile_r1, ntiles, act);
  moe_gemm2<<<G2_BLOCKS, 256, 0, stream>>>(act, wdt,
      tile_e, tile_r0, tile_r1, ntiles, y);
  moe_combine<<<T_TOK, 256, 0, stream>>>(y, inv, wt_s, out);
}